// Round 5
// baseline (510.859 us; speedup 1.0000x reference)
//
#include <hip/hip_runtime.h>
#include <math.h>

// MultiPerspectiveMatch on MI355X — round 15.
// vs r14 (k_big still 128-VGPR/spilling despite ~55-reg maxpool live set):
// three rounds prove the shared maxpool+gemm2 kernel is the allocation
// problem (worst path sets pressure for both; allocator won't exceed 128).
//  - SPLIT: k_max (maxpool only, plain __launch_bounds__(512), 90.7KB LDS,
//    jt loop pinned #pragma unroll 1 to stop the 13x7 ds_read unroll-hoist)
//    and k_gemm2 (exact r10-proven body, own kernel, (512,2) -> 120 VGPR,
//    zero scratch in r10).
//  - q tile cut to 208 rows (all that jt=0..12 reads): 97.7 -> 90.7 KB.
//  - numerics byte-identical to r14 (passed, absmax 2^-8).
//  - per-kernel counters now isolate any remaining spill to one role.

#define EPS 1e-6f
#define NEG_HUGE -3.4e38f

typedef __bf16 bf16x8 __attribute__((ext_vector_type(8)));
typedef float f32x4 __attribute__((ext_vector_type(4)));
typedef float f32x16 __attribute__((ext_vector_type(16)));

// ---- ws offsets (floats) ----
constexpr size_t OFF_M2ALL = 0;            // f32 [4][50][200] = 40,000
constexpr size_t OFF_M2B16 = 40000;        // bf16 [224][208] = 23,296 fl
constexpr size_t OFF_QB16  = 63296;        // bf16 [32][256][208] = 851,968 fl
constexpr size_t OFF_DB16  = 915264;       // bf16 [32][256][208] = 851,968 fl
constexpr size_t OFF_INVFPN= 1767232;      // [6400][50]
constexpr size_t OFF_INVMPN= 2087232;
constexpr size_t OFF_INVAPN= 2407232;
constexpr size_t OFF_INVXPN= 2727232;
constexpr size_t OFF_INVMQN= 3047232;      // [c(50)][6400]
constexpr size_t OFF_INVXQN= 3367232;      // [6400][50]
constexpr size_t OFF_INVFQN= 3687232;      // [32][50]
constexpr size_t OFF_INVDN = 3688832;      // [6400]
constexpr size_t OFF_INVQN = 3695232;      // [6400]
constexpr size_t OFF_IDX   = 3701632;      // int [6400]
constexpr size_t OFF_WQ    = 3708032;      // [32][200][200] = 1,280,000
constexpr size_t OFF_G     = 4988032;      // [4][6400][50] = 1,280,000
constexpr size_t OFF_PMAX2 = 6268032;      // [1600][256]
constexpr size_t OFF_PSUM2 = 6677632;      // [1600][256]
// end = 7,087,232 floats = 28.3 MB

// Fused prep: blocks [0,4096): d/q rows -> bf16 padded [32][256][208] + plain
// norms (one row per wave). Blocks [4096, 4278): M^2 tables (f32 + bf16).
__global__ __launch_bounds__(256) void k_prep(
    const float* __restrict__ qR, const float* __restrict__ dR,
    const float* __restrict__ fM, const float* __restrict__ mM,
    const float* __restrict__ aM, const float* __restrict__ xM,
    unsigned short* __restrict__ qb16, unsigned short* __restrict__ db16,
    float* __restrict__ invdn, float* __restrict__ invqn,
    float* __restrict__ m2all, unsigned short* __restrict__ m2b16)
{
  int blk = blockIdx.x;
  int tid = threadIdx.x;
  if (blk < 4096) {
    int task = blk*4 + (tid >> 6);        // 0..16383
    int l = tid & 63;
    int isQ = task >= 8192;
    int r = isQ ? task - 8192 : task;     // b*256 + j
    int b = r >> 8, j = r & 255;
    unsigned short* dst = (isQ ? qb16 : db16) + (size_t)r*208;
    if (j < 200) {
      const float* src = (isQ ? qR : dR) + (size_t)(b*200 + j)*200;
      float4 v = {0.f,0.f,0.f,0.f};
      if (l < 50) v = *(const float4*)(src + l*4);
      float s = fmaf(v.x,v.x, fmaf(v.y,v.y, fmaf(v.z,v.z, v.w*v.w)));
#pragma unroll
      for (int m = 32; m; m >>= 1) s += __shfl_xor(s, m);
      if (l == 0) {
        float rr = rsqrtf(fmaxf(s, EPS));
        if (isQ) invqn[b*200 + j] = rr; else invdn[b*200 + j] = rr;
      }
      if (l < 52) {
        ushort4 o = {0,0,0,0};
        if (l < 50) {
          __bf16 h0=(__bf16)v.x, h1=(__bf16)v.y, h2=(__bf16)v.z, h3=(__bf16)v.w;
          o.x = *(unsigned short*)&h0; o.y = *(unsigned short*)&h1;
          o.z = *(unsigned short*)&h2; o.w = *(unsigned short*)&h3;
        }
        *(ushort4*)(dst + l*4) = o;
      }
    } else {
      if (l < 52) { ushort4 z = {0,0,0,0}; *(ushort4*)(dst + l*4) = z; }
    }
  } else {
    int i = (blk - 4096)*256 + tid;
    if (i < 40000) {
      int m = i / 10000, r = i % 10000;
      const float* s = (m==0)?fM:(m==1)?mM:(m==2)?aM:xM;
      float v = s[r];
      m2all[i] = v*v;
    }
    if (i < 224*208) {
      int row = i / 208, k = i % 208;
      unsigned short o = 0;
      if (row < 200 && k < 200) {
        int m = row / 50, c = row % 50;
        const float* s = (m==0)?fM:(m==1)?mM:(m==2)?aM:xM;
        float v = s[c*200 + k];
        __bf16 h = (__bf16)(v*v);
        o = *(unsigned short*)&h;
      }
      m2b16[i] = o;
    }
  }
}

// k_mid: blocks [0,702) = gemm1 (nsq MFMA + fused rsqrt/scatter, one wave per
// (row-tile,nt), 2807 tasks); blocks [702,1502) = relwq (rel+wq fused, v3:
// per-lane direct global q rows, no qsh staging; relsh stays in LDS).
__global__ __launch_bounds__(256) void k_mid(
    const float* __restrict__ dR, const float* __restrict__ qR,
    const float* __restrict__ qL, const unsigned short* __restrict__ m2b16,
    float* __restrict__ invfpn, float* __restrict__ invmpn,
    float* __restrict__ invapn, float* __restrict__ invxpn,
    float* __restrict__ invmqn, float* __restrict__ invxqn,
    float* __restrict__ invfqn,
    const float* __restrict__ qMask, const float* __restrict__ dMask,
    const float* __restrict__ invdn, const float* __restrict__ invqn,
    float* __restrict__ wq, int* __restrict__ idxout)
{
  int tid = threadIdx.x;
  if (blockIdx.x < 702) {
    // ---------------- gemm1 role ----------------
    int w = tid >> 6, lane = tid & 63;
    int n = lane & 31, h = lane >> 5;
    int task = blockIdx.x*4 + w;
    if (task >= 2807) return;             // wave-uniform
    int rt = task / 7, nt = task % 7;     // rt in [0,401), 401*32 = 12832
    int row = rt*32 + n;

    const float* src;
    if (row < 6400)       src = dR + (size_t)row*200;
    else if (row < 12800) src = qR + (size_t)(row-6400)*200;
    else                  src = qL + (size_t)(row-12800)*200;

    bf16x8 afrag[13];
#pragma unroll
    for (int ks = 0; ks < 13; ks++) {
      int ko = ks*16 + h*8;
      bf16x8 af;
      if (ko < 200) {
        float4 a0 = *(const float4*)(src + ko);
        float4 a1 = *(const float4*)(src + ko + 4);
        af[0] = (__bf16)(a0.x*a0.x); af[1] = (__bf16)(a0.y*a0.y);
        af[2] = (__bf16)(a0.z*a0.z); af[3] = (__bf16)(a0.w*a0.w);
        af[4] = (__bf16)(a1.x*a1.x); af[5] = (__bf16)(a1.y*a1.y);
        af[6] = (__bf16)(a1.z*a1.z); af[7] = (__bf16)(a1.w*a1.w);
      } else {
#pragma unroll
        for (int z = 0; z < 8; z++) af[z] = (__bf16)0.0f;
      }
      afrag[ks] = af;
    }

    f32x16 C;
#pragma unroll
    for (int z = 0; z < 16; z++) C[z] = 0.f;
    const unsigned short* bp = m2b16 + (size_t)(nt*32 + n)*208 + h*8;
#pragma unroll
    for (int ks = 0; ks < 13; ks++) {
      bf16x8 bf = *(const bf16x8*)(bp + ks*16);
      C = __builtin_amdgcn_mfma_f32_32x32x16_bf16(afrag[ks], bf, C, 0, 0, 0);
    }

    int cp = nt*32 + n;                   // c' = m*50 + c
    if (cp < 200) {
      int m = cp / 50, c = cp % 50;
#pragma unroll
      for (int r = 0; r < 16; r++) {
        int grow = rt*32 + (r & 3) + 8*(r >> 2) + 4*h;
        float v = rsqrtf(fmaxf(C[r], EPS));
        if (grow < 6400) {
          if (m == 0)      invfpn[grow*50 + c] = v;
          else if (m == 1) invmpn[grow*50 + c] = v;
          else if (m == 2) invapn[grow*50 + c] = v;
          else             invxpn[grow*50 + c] = v;
        } else if (grow < 12800) {
          int r2 = grow - 6400;
          if (m == 1)      invmqn[c*6400 + r2] = v;
          else if (m == 3) invxqn[r2*50 + c] = v;
        } else {
          if (m == 0)      invfqn[(grow-12800)*50 + c] = v;
        }
      }
    }
  } else {
    // ---------------- relwq role ----------------
    __shared__ float relsh[8][256];            // 8 KB
    __shared__ float redv[4][8][2];
    __shared__ int   redi[4][8];
    __shared__ float invrs_sh[8];
    int blk = blockIdx.x - 702;
    int b  = blk / 25;
    int i0 = (blk % 25) * 8;
    int j = tid, jr = min(j, 199);
    bool jv = j < 200;
    const float* qb = qR + b*40000;
    const float* db = dR + (b*200 + i0)*200;
    float acc[8];
#pragma unroll
    for (int ii = 0; ii < 8; ii++) acc[ii] = 0.f;

    // phase 1: lane=j, q row read direct from global (L2-resident).
    const float* qrow = qb + jr*200;
    for (int k4 = 0; k4 < 200; k4 += 4) {
      float4 qv = *(const float4*)(qrow + k4);
#pragma unroll
      for (int ii = 0; ii < 8; ii++) {
        acc[ii] = fmaf(db[ii*200 + k4 + 0], qv.x, acc[ii]);
        acc[ii] = fmaf(db[ii*200 + k4 + 1], qv.y, acc[ii]);
        acc[ii] = fmaf(db[ii*200 + k4 + 2], qv.z, acc[ii]);
        acc[ii] = fmaf(db[ii*200 + k4 + 3], qv.w, acc[ii]);
      }
    }

    float iqn = invqn[b*200 + jr];
    float qm  = qMask[b*200 + jr];
    int w = tid >> 6, l = tid & 63;
    float rv[8];
#pragma unroll
    for (int ii = 0; ii < 8; ii++) {
      float idn = invdn[b*200 + i0 + ii];
      float dm  = dMask[b*200 + i0 + ii];
      float r = acc[ii]*iqn*idn*qm*dm;
      rv[ii] = r;
      relsh[ii][j] = jv ? r : 0.f;
    }
#pragma unroll
    for (int ii = 0; ii < 8; ii++) {
      float vm = jv ? rv[ii] : NEG_HUGE;
      float vs = jv ? rv[ii] : 0.f;
      int bj = jr;
#pragma unroll
      for (int m = 32; m; m >>= 1) {
        float ov = __shfl_xor(vm, m);
        int   oj = __shfl_xor(bj, m);
        vs += __shfl_xor(vs, m);
        if (ov > vm || (ov == vm && oj < bj)) { vm = ov; bj = oj; }  // first-max
      }
      if (l == 0) { redv[w][ii][0] = vm; redv[w][ii][1] = vs; redi[w][ii] = bj; }
    }
    __syncthreads();
    if (tid < 8) {
      float bv = redv[0][tid][0], ss = redv[0][tid][1]; int bj = redi[0][tid];
      for (int w2 = 1; w2 < 4; w2++) {
        ss += redv[w2][tid][1];
        float wv = redv[w2][tid][0]; int wj = redi[w2][tid];
        if (wv > bv || (wv == bv && wj < bj)) { bv = wv; bj = wj; }
      }
      invrs_sh[tid] = 1.f/(ss + EPS);
      idxout[b*200 + i0 + tid] = bj;
    }
    __syncthreads();

    // phase 2: lane = k
    int kl = min(tid, 199); bool kv = tid < 200;
    float acw[8];
#pragma unroll
    for (int ii = 0; ii < 8; ii++) acw[ii] = 0.f;
    for (int j0 = 0; j0 < 200; j0 += 4) {
      float qv0 = qb[(j0+0)*200 + kl];
      float qv1 = qb[(j0+1)*200 + kl];
      float qv2 = qb[(j0+2)*200 + kl];
      float qv3 = qb[(j0+3)*200 + kl];
#pragma unroll
      for (int ii = 0; ii < 8; ii++) {
        float4 rs = *(const float4*)&relsh[ii][j0];
        acw[ii] = fmaf(rs.x, qv0, acw[ii]);
        acw[ii] = fmaf(rs.y, qv1, acw[ii]);
        acw[ii] = fmaf(rs.z, qv2, acw[ii]);
        acw[ii] = fmaf(rs.w, qv3, acw[ii]);
      }
    }
#pragma unroll
    for (int ii = 0; ii < 8; ii++) {
      float v = acw[ii]*invrs_sh[ii];
      if (kv) wq[(size_t)(b*200 + i0 + ii)*200 + tid] = v;
    }
  }
}

// k_max: maxpool only (v15). 320 blocks (32 b x 10 cgroups of 5 c), 512 thr.
// 16x16x32 engine; q tile 208 rows x stride 218 (90.7KB); jt loop unroll 1.
__global__ __launch_bounds__(512) void k_max(
    const unsigned short* __restrict__ db16, const unsigned short* __restrict__ qb16,
    const float* __restrict__ m2all, const float* __restrict__ invmqn,
    float* __restrict__ pmax2, float* __restrict__ psum2)
{
  __shared__ __align__(16) unsigned short qsh[208*218 + 8];  // 90,704 B
  __shared__ __align__(16) float m2sh[5*224];                // k>=200 zeroed
  __shared__ float iqsh[5*208];                              // j>=200 zeroed
  int tid = threadIdx.x;
  int w = tid >> 6, lane = tid & 63;
  int b = blockIdx.x / 10, cg = blockIdx.x % 10;

  {
    const unsigned short* src = qb16 + (size_t)b*256*208;
    for (int s = tid; s < 208*26; s += 512) {
      int r = s / 26, ch = s - r*26;
      *(bf16x8*)(qsh + r*218 + ch*8) =
          *(const bf16x8*)(src + (size_t)r*208 + ch*8);
    }
    // zero row pads [208,218) (5 x uint per row) and the 8-elem tail
    for (int s = tid; s < 208*5; s += 512) {
      int r = s / 5, p = s - r*5;
      *(unsigned int*)(qsh + r*218 + 208 + p*2) = 0u;
    }
    if (tid < 4) *(unsigned int*)(qsh + 208*218 + tid*2) = 0u;
    for (int s = tid; s < 5*224; s += 512) {
      int cl = s / 224, k = s - cl*224;
      m2sh[s] = (k < 200) ? m2all[10000 + (cg*5 + cl)*200 + k] : 0.f;
    }
    for (int s = tid; s < 5*208; s += 512) {
      int cl = s / 208, jj = s - cl*208;
      iqsh[s] = (jj < 200) ? invmqn[(size_t)(cg*5 + cl)*6400 + b*200 + jj] : 0.f;
    }
  }
  __syncthreads();

  int r16 = lane & 15, g = lane >> 4;      // A-row / B-col index; k-octet
  bool hi_ok = g < 2;                       // chunk-6 k in [192,208) valid
  // 65 tasks: (i-16-tile in [0,13)) x (c-local in [0,5)).
  for (int t = w; t < 65; t += 8) {
    int it = t % 13, cl = t / 13;
    int c = cg*5 + cl;

    // A-fragments: bf16 d row, scaled in place by m2 (f32 LDS).
    const unsigned short* dbp =
        db16 + (size_t)(b*256 + it*16 + r16)*208 + g*8;
    const float* m2p = m2sh + cl*224 + g*8;
    bf16x8 afc[7];
#pragma unroll
    for (int ks = 0; ks < 6; ks++) afc[ks] = *(const bf16x8*)(dbp + ks*32);
    afc[6] = *(const bf16x8*)(dbp + (hi_ok ? 192 : 0));
#pragma unroll
    for (int ks = 0; ks < 7; ks++) {
      float4 m0 = *(const float4*)(m2p + ks*32);
      float4 m1 = *(const float4*)(m2p + ks*32 + 4);
      bf16x8 a = afc[ks];
      a[0] = (__bf16)((float)a[0]*m0.x); a[1] = (__bf16)((float)a[1]*m0.y);
      a[2] = (__bf16)((float)a[2]*m0.z); a[3] = (__bf16)((float)a[3]*m0.w);
      a[4] = (__bf16)((float)a[4]*m1.x); a[5] = (__bf16)((float)a[5]*m1.y);
      a[6] = (__bf16)((float)a[6]*m1.z); a[7] = (__bf16)((float)a[7]*m1.w);
      afc[ks] = a;
    }

    float vm[4], vs[4];
#pragma unroll
    for (int r = 0; r < 4; r++) { vm[r] = NEG_HUGE; vs[r] = 0.f; }
    const float* iqp = iqsh + cl*208;

#pragma unroll 1
    for (int jt = 0; jt < 13; jt++) {       // 13 j-16-tiles (208 cols)
      f32x4 C;
#pragma unroll
      for (int z = 0; z < 4; z++) C[z] = 0.f;
      const unsigned short* bptr = qsh + (jt*16 + r16)*218 + g*8;
#pragma unroll
      for (int ks = 0; ks < 7; ks++) {
        bf16x8 bf = *(const bf16x8*)(bptr + ks*32);
        C = __builtin_amdgcn_mfma_f32_16x16x32_bf16(afc[ks], bf, C, 0, 0, 0);
      }
      int j = jt*16 + r16;                  // this lane's C column
      bool jvld = j < 200;
      float iqj = iqp[j];                   // zero-padded for j>=200
#pragma unroll
      for (int r = 0; r < 4; r++) {
        float v = C[r]*iqj;
        vs[r] += v;                          // j>=200: C=0 and iqj=0
        vm[r] = fmaxf(vm[r], jvld ? v : NEG_HUGE);
      }
    }

    // reduce over j (across the 16-lane col groups; row-group g preserved)
#pragma unroll
    for (int r = 0; r < 4; r++) {
      float a2 = vm[r], s2 = vs[r];
#pragma unroll
      for (int m = 1; m <= 8; m <<= 1) {
        a2 = fmaxf(a2, __shfl_xor(a2, m));
        s2 += __shfl_xor(s2, m);
      }
      vm[r] = a2; vs[r] = s2;
    }
    if (r16 == 0) {
      size_t base = (size_t)(b*50 + c)*256;
#pragma unroll
      for (int r = 0; r < 4; r++) {
        int i = it*16 + g*4 + r;             // C row = g*4 + reg
        pmax2[base + i] = vm[r];
        psum2[base + i] = vs[r];
      }
    }
  }
}

// k_gemm2: exact r10-proven body, own kernel. 200 blocks x 512 thr,
// 8 wave-tasks per block, 1600 tasks.
__global__ __launch_bounds__(512,2) void k_gemm2(
    const float* __restrict__ dR, const float* __restrict__ qR,
    const float* __restrict__ qL, const float* __restrict__ wq,
    const int* __restrict__ idx, const unsigned short* __restrict__ m2b16,
    float* __restrict__ G)
{
  int tid = threadIdx.x;
  int w = tid >> 6, lane = tid & 63;
  int n = lane & 31, h = lane >> 5;
  int task = blockIdx.x*8 + w;             // [0,1600)
  int mp = task / 400;
  int sub = task % 400;
  int rt = sub >> 1, nt = sub & 1;
  int row = rt*32 + n;                     // < 6400
  int bb = row / 200;
  int msel = (mp == 0) ? 0 : (mp == 3) ? 3 : 2;

  const float* s0 = dR + (size_t)row*200;
  const float* s1;
  if (mp == 0)      s1 = qL + (size_t)bb*200;
  else if (mp == 1) s1 = wq + (size_t)row*200;
  else if (mp == 2) { s0 = wq + (size_t)row*200; s1 = s0; }
  else              s1 = qR + (size_t)(bb*200 + idx[row])*200;

  bf16x8 afrag[13];
#pragma unroll
  for (int ks = 0; ks < 13; ks++) {
    int ko = ks*16 + h*8;
    bf16x8 af;
    if (ko < 200) {
      float4 a0 = *(const float4*)(s0 + ko);
      float4 a1 = *(const float4*)(s0 + ko + 4);
      float4 b0 = *(const float4*)(s1 + ko);
      float4 b1 = *(const float4*)(s1 + ko + 4);
      af[0] = (__bf16)(a0.x*b0.x); af[1] = (__bf16)(a0.y*b0.y);
      af[2] = (__bf16)(a0.z*b0.z); af[3] = (__bf16)(a0.w*b0.w);
      af[4] = (__bf16)(a1.x*b1.x); af[5] = (__bf16)(a1.y*b1.y);
      af[6] = (__bf16)(a1.z*b1.z); af[7] = (__bf16)(a1.w*b1.w);
    } else {
#pragma unroll
      for (int z = 0; z < 8; z++) af[z] = (__bf16)0.0f;
    }
    afrag[ks] = af;
  }

  f32x16 C;
#pragma unroll
  for (int z = 0; z < 16; z++) C[z] = 0.f;
  const unsigned short* bp = m2b16 + (size_t)(msel*50 + nt*32 + n)*208 + h*8;
#pragma unroll
  for (int ks = 0; ks < 13; ks++) {
    bf16x8 bf = *(const bf16x8*)(bp + ks*16);
    C = __builtin_amdgcn_mfma_f32_32x32x16_bf16(afrag[ks], bf, C, 0, 0, 0);
  }
  int cc = nt*32 + n;
  if (cc < 50) {
#pragma unroll
    for (int r = 0; r < 16; r++) {
      int mrow = (r & 3) + 8*(r >> 2) + 4*h;
      G[(size_t)(mp*6400 + rt*32 + mrow)*50 + cc] = C[r];
    }
  }
}

// Final assembly: out[row][0:250] written lane-coalesced.
__global__ void k_out(
    const float* __restrict__ G, const float* __restrict__ pmax2,
    const float* __restrict__ psum2, const float* __restrict__ invfpn,
    const float* __restrict__ invmpn, const float* __restrict__ invapn,
    const float* __restrict__ invxpn, const float* __restrict__ invfqn,
    const float* __restrict__ invxqn, const int* __restrict__ idx,
    float* __restrict__ out)
{
  int row = blockIdx.x;
  int l = threadIdx.x;
  if (l >= 250) return;
  int b = row / 200, i = row % 200;
  int seg = l / 50, c = l % 50;
  float o;
  if (seg == 0) {
    o = G[(size_t)(0*6400 + row)*50 + c] * invfpn[row*50 + c] * invfqn[b*50 + c];
  } else if (seg == 1) {
    o = pmax2[(size_t)(b*50 + c)*256 + i] * invmpn[row*50 + c];
  } else if (seg == 2) {
    o = psum2[(size_t)(b*50 + c)*256 + i] * invmpn[row*50 + c] * (1.f/200.f);
  } else if (seg == 3) {
    o = G[(size_t)(1*6400 + row)*50 + c] * invapn[row*50 + c]
        * rsqrtf(fmaxf(G[(size_t)(2*6400 + row)*50 + c], EPS));
  } else {
    int jid = idx[row];
    o = G[(size_t)(3*6400 + row)*50 + c] * invxpn[row*50 + c]
        * invxqn[(b*200 + jid)*50 + c];
  }
  out[(size_t)row*250 + l] = o;
}

extern "C" void kernel_launch(void* const* d_in, const int* in_sizes, int n_in,
                              void* d_out, int out_size, void* d_ws, size_t ws_size,
                              hipStream_t stream) {
  const float* qR = (const float*)d_in[0];
  const float* qL = (const float*)d_in[1];
  const float* qM = (const float*)d_in[2];
  const float* dR = (const float*)d_in[3];
  // d_in[4] = d_last: unused by the reference
  const float* dM = (const float*)d_in[5];
  const float* fullM = (const float*)d_in[6];
  const float* mpM   = (const float*)d_in[7];
  const float* attM  = (const float*)d_in[8];
  const float* xM    = (const float*)d_in[9];

  float* ws  = (float*)d_ws;
  float* out = (float*)d_out;

  float* m2all  = ws + OFF_M2ALL;
  unsigned short* m2b16 = (unsigned short*)(ws + OFF_M2B16);
  unsigned short* qb16 = (unsigned short*)(ws + OFF_QB16);
  unsigned short* db16 = (unsigned short*)(ws + OFF_DB16);
  float* invfpn = ws + OFF_INVFPN;
  float* invmpn = ws + OFF_INVMPN;
  float* invapn = ws + OFF_INVAPN;
  float* invxpn = ws + OFF_INVXPN;
  float* invmqn = ws + OFF_INVMQN;
  float* invxqn = ws + OFF_INVXQN;
  float* invfqn = ws + OFF_INVFQN;
  float* invdn  = ws + OFF_INVDN;
  float* invqn  = ws + OFF_INVQN;
  int*   idxp   = (int*)(ws + OFF_IDX);
  float* wqp    = ws + OFF_WQ;
  float* G      = ws + OFF_G;
  float* pmax2  = ws + OFF_PMAX2;
  float* psum2  = ws + OFF_PSUM2;

  k_prep<<<4278, 256, 0, stream>>>(qR, dR, fullM, mpM, attM, xM,
                                   qb16, db16, invdn, invqn, m2all, m2b16);
  k_mid<<<1502, 256, 0, stream>>>(dR, qR, qL, m2b16,
                                  invfpn, invmpn, invapn, invxpn,
                                  invmqn, invxqn, invfqn,
                                  qM, dM, invdn, invqn, wqp, idxp);
  k_max<<<320, 512, 0, stream>>>(db16, qb16, m2all, invmqn, pmax2, psum2);
  k_gemm2<<<200, 512, 0, stream>>>(dR, qR, qL, wqp, idxp, m2b16, G);
  k_out<<<6400, 256, 0, stream>>>(G, pmax2, psum2, invfpn, invmpn, invapn,
                                  invxpn, invfqn, invxqn, idxp, out);
}

// Round 6
// 488.241 us; speedup vs baseline: 1.0463x; 1.0463x over previous
//
#include <hip/hip_runtime.h>
#include <math.h>

// MultiPerspectiveMatch on MI355X — round 16.
// vs r15 (k_max 358us, NO spill, MfmaUtil 3.4% -> pure latency: 845 jt-iters
// x ~500cyc serial chain [lgkm drain + 7-deep dependent MFMA] at 2 waves/SIMD):
//  - jt loop -> 6 PAIRS of j-tiles with independent C0/C1 accumulator chains
//    (2-way MFMA ILP, ds_reads of both tiles batched) + guarded tail (jt=12).
//    Pair loop pinned #pragma unroll 1 -> live set ~120 regs, bounded.
//  - pairs cover j<=191 -> validity guards dropped there; accumulation order
//    preserved exactly -> bit-identical to r15 (passed, absmax 2^-8).
//  - everything else byte-identical to r15 (split kernels kept).

#define EPS 1e-6f
#define NEG_HUGE -3.4e38f

typedef __bf16 bf16x8 __attribute__((ext_vector_type(8)));
typedef float f32x4 __attribute__((ext_vector_type(4)));
typedef float f32x16 __attribute__((ext_vector_type(16)));

// ---- ws offsets (floats) ----
constexpr size_t OFF_M2ALL = 0;            // f32 [4][50][200] = 40,000
constexpr size_t OFF_M2B16 = 40000;        // bf16 [224][208] = 23,296 fl
constexpr size_t OFF_QB16  = 63296;        // bf16 [32][256][208] = 851,968 fl
constexpr size_t OFF_DB16  = 915264;       // bf16 [32][256][208] = 851,968 fl
constexpr size_t OFF_INVFPN= 1767232;      // [6400][50]
constexpr size_t OFF_INVMPN= 2087232;
constexpr size_t OFF_INVAPN= 2407232;
constexpr size_t OFF_INVXPN= 2727232;
constexpr size_t OFF_INVMQN= 3047232;      // [c(50)][6400]
constexpr size_t OFF_INVXQN= 3367232;      // [6400][50]
constexpr size_t OFF_INVFQN= 3687232;      // [32][50]
constexpr size_t OFF_INVDN = 3688832;      // [6400]
constexpr size_t OFF_INVQN = 3695232;      // [6400]
constexpr size_t OFF_IDX   = 3701632;      // int [6400]
constexpr size_t OFF_WQ    = 3708032;      // [32][200][200] = 1,280,000
constexpr size_t OFF_G     = 4988032;      // [4][6400][50] = 1,280,000
constexpr size_t OFF_PMAX2 = 6268032;      // [1600][256]
constexpr size_t OFF_PSUM2 = 6677632;      // [1600][256]
// end = 7,087,232 floats = 28.3 MB

// Fused prep: blocks [0,4096): d/q rows -> bf16 padded [32][256][208] + plain
// norms (one row per wave). Blocks [4096, 4278): M^2 tables (f32 + bf16).
__global__ __launch_bounds__(256) void k_prep(
    const float* __restrict__ qR, const float* __restrict__ dR,
    const float* __restrict__ fM, const float* __restrict__ mM,
    const float* __restrict__ aM, const float* __restrict__ xM,
    unsigned short* __restrict__ qb16, unsigned short* __restrict__ db16,
    float* __restrict__ invdn, float* __restrict__ invqn,
    float* __restrict__ m2all, unsigned short* __restrict__ m2b16)
{
  int blk = blockIdx.x;
  int tid = threadIdx.x;
  if (blk < 4096) {
    int task = blk*4 + (tid >> 6);        // 0..16383
    int l = tid & 63;
    int isQ = task >= 8192;
    int r = isQ ? task - 8192 : task;     // b*256 + j
    int b = r >> 8, j = r & 255;
    unsigned short* dst = (isQ ? qb16 : db16) + (size_t)r*208;
    if (j < 200) {
      const float* src = (isQ ? qR : dR) + (size_t)(b*200 + j)*200;
      float4 v = {0.f,0.f,0.f,0.f};
      if (l < 50) v = *(const float4*)(src + l*4);
      float s = fmaf(v.x,v.x, fmaf(v.y,v.y, fmaf(v.z,v.z, v.w*v.w)));
#pragma unroll
      for (int m = 32; m; m >>= 1) s += __shfl_xor(s, m);
      if (l == 0) {
        float rr = rsqrtf(fmaxf(s, EPS));
        if (isQ) invqn[b*200 + j] = rr; else invdn[b*200 + j] = rr;
      }
      if (l < 52) {
        ushort4 o = {0,0,0,0};
        if (l < 50) {
          __bf16 h0=(__bf16)v.x, h1=(__bf16)v.y, h2=(__bf16)v.z, h3=(__bf16)v.w;
          o.x = *(unsigned short*)&h0; o.y = *(unsigned short*)&h1;
          o.z = *(unsigned short*)&h2; o.w = *(unsigned short*)&h3;
        }
        *(ushort4*)(dst + l*4) = o;
      }
    } else {
      if (l < 52) { ushort4 z = {0,0,0,0}; *(ushort4*)(dst + l*4) = z; }
    }
  } else {
    int i = (blk - 4096)*256 + tid;
    if (i < 40000) {
      int m = i / 10000, r = i % 10000;
      const float* s = (m==0)?fM:(m==1)?mM:(m==2)?aM:xM;
      float v = s[r];
      m2all[i] = v*v;
    }
    if (i < 224*208) {
      int row = i / 208, k = i % 208;
      unsigned short o = 0;
      if (row < 200 && k < 200) {
        int m = row / 50, c = row % 50;
        const float* s = (m==0)?fM:(m==1)?mM:(m==2)?aM:xM;
        float v = s[c*200 + k];
        __bf16 h = (__bf16)(v*v);
        o = *(unsigned short*)&h;
      }
      m2b16[i] = o;
    }
  }
}

// k_mid: blocks [0,702) = gemm1 (nsq MFMA + fused rsqrt/scatter, one wave per
// (row-tile,nt), 2807 tasks); blocks [702,1502) = relwq (rel+wq fused, v3:
// per-lane direct global q rows, no qsh staging; relsh stays in LDS).
__global__ __launch_bounds__(256) void k_mid(
    const float* __restrict__ dR, const float* __restrict__ qR,
    const float* __restrict__ qL, const unsigned short* __restrict__ m2b16,
    float* __restrict__ invfpn, float* __restrict__ invmpn,
    float* __restrict__ invapn, float* __restrict__ invxpn,
    float* __restrict__ invmqn, float* __restrict__ invxqn,
    float* __restrict__ invfqn,
    const float* __restrict__ qMask, const float* __restrict__ dMask,
    const float* __restrict__ invdn, const float* __restrict__ invqn,
    float* __restrict__ wq, int* __restrict__ idxout)
{
  int tid = threadIdx.x;
  if (blockIdx.x < 702) {
    // ---------------- gemm1 role ----------------
    int w = tid >> 6, lane = tid & 63;
    int n = lane & 31, h = lane >> 5;
    int task = blockIdx.x*4 + w;
    if (task >= 2807) return;             // wave-uniform
    int rt = task / 7, nt = task % 7;     // rt in [0,401), 401*32 = 12832
    int row = rt*32 + n;

    const float* src;
    if (row < 6400)       src = dR + (size_t)row*200;
    else if (row < 12800) src = qR + (size_t)(row-6400)*200;
    else                  src = qL + (size_t)(row-12800)*200;

    bf16x8 afrag[13];
#pragma unroll
    for (int ks = 0; ks < 13; ks++) {
      int ko = ks*16 + h*8;
      bf16x8 af;
      if (ko < 200) {
        float4 a0 = *(const float4*)(src + ko);
        float4 a1 = *(const float4*)(src + ko + 4);
        af[0] = (__bf16)(a0.x*a0.x); af[1] = (__bf16)(a0.y*a0.y);
        af[2] = (__bf16)(a0.z*a0.z); af[3] = (__bf16)(a0.w*a0.w);
        af[4] = (__bf16)(a1.x*a1.x); af[5] = (__bf16)(a1.y*a1.y);
        af[6] = (__bf16)(a1.z*a1.z); af[7] = (__bf16)(a1.w*a1.w);
      } else {
#pragma unroll
        for (int z = 0; z < 8; z++) af[z] = (__bf16)0.0f;
      }
      afrag[ks] = af;
    }

    f32x16 C;
#pragma unroll
    for (int z = 0; z < 16; z++) C[z] = 0.f;
    const unsigned short* bp = m2b16 + (size_t)(nt*32 + n)*208 + h*8;
#pragma unroll
    for (int ks = 0; ks < 13; ks++) {
      bf16x8 bf = *(const bf16x8*)(bp + ks*16);
      C = __builtin_amdgcn_mfma_f32_32x32x16_bf16(afrag[ks], bf, C, 0, 0, 0);
    }

    int cp = nt*32 + n;                   // c' = m*50 + c
    if (cp < 200) {
      int m = cp / 50, c = cp % 50;
#pragma unroll
      for (int r = 0; r < 16; r++) {
        int grow = rt*32 + (r & 3) + 8*(r >> 2) + 4*h;
        float v = rsqrtf(fmaxf(C[r], EPS));
        if (grow < 6400) {
          if (m == 0)      invfpn[grow*50 + c] = v;
          else if (m == 1) invmpn[grow*50 + c] = v;
          else if (m == 2) invapn[grow*50 + c] = v;
          else             invxpn[grow*50 + c] = v;
        } else if (grow < 12800) {
          int r2 = grow - 6400;
          if (m == 1)      invmqn[c*6400 + r2] = v;
          else if (m == 3) invxqn[r2*50 + c] = v;
        } else {
          if (m == 0)      invfqn[(grow-12800)*50 + c] = v;
        }
      }
    }
  } else {
    // ---------------- relwq role ----------------
    __shared__ float relsh[8][256];            // 8 KB
    __shared__ float redv[4][8][2];
    __shared__ int   redi[4][8];
    __shared__ float invrs_sh[8];
    int blk = blockIdx.x - 702;
    int b  = blk / 25;
    int i0 = (blk % 25) * 8;
    int j = tid, jr = min(j, 199);
    bool jv = j < 200;
    const float* qb = qR + b*40000;
    const float* db = dR + (b*200 + i0)*200;
    float acc[8];
#pragma unroll
    for (int ii = 0; ii < 8; ii++) acc[ii] = 0.f;

    // phase 1: lane=j, q row read direct from global (L2-resident).
    const float* qrow = qb + jr*200;
    for (int k4 = 0; k4 < 200; k4 += 4) {
      float4 qv = *(const float4*)(qrow + k4);
#pragma unroll
      for (int ii = 0; ii < 8; ii++) {
        acc[ii] = fmaf(db[ii*200 + k4 + 0], qv.x, acc[ii]);
        acc[ii] = fmaf(db[ii*200 + k4 + 1], qv.y, acc[ii]);
        acc[ii] = fmaf(db[ii*200 + k4 + 2], qv.z, acc[ii]);
        acc[ii] = fmaf(db[ii*200 + k4 + 3], qv.w, acc[ii]);
      }
    }

    float iqn = invqn[b*200 + jr];
    float qm  = qMask[b*200 + jr];
    int w = tid >> 6, l = tid & 63;
    float rv[8];
#pragma unroll
    for (int ii = 0; ii < 8; ii++) {
      float idn = invdn[b*200 + i0 + ii];
      float dm  = dMask[b*200 + i0 + ii];
      float r = acc[ii]*iqn*idn*qm*dm;
      rv[ii] = r;
      relsh[ii][j] = jv ? r : 0.f;
    }
#pragma unroll
    for (int ii = 0; ii < 8; ii++) {
      float vm = jv ? rv[ii] : NEG_HUGE;
      float vs = jv ? rv[ii] : 0.f;
      int bj = jr;
#pragma unroll
      for (int m = 32; m; m >>= 1) {
        float ov = __shfl_xor(vm, m);
        int   oj = __shfl_xor(bj, m);
        vs += __shfl_xor(vs, m);
        if (ov > vm || (ov == vm && oj < bj)) { vm = ov; bj = oj; }  // first-max
      }
      if (l == 0) { redv[w][ii][0] = vm; redv[w][ii][1] = vs; redi[w][ii] = bj; }
    }
    __syncthreads();
    if (tid < 8) {
      float bv = redv[0][tid][0], ss = redv[0][tid][1]; int bj = redi[0][tid];
      for (int w2 = 1; w2 < 4; w2++) {
        ss += redv[w2][tid][1];
        float wv = redv[w2][tid][0]; int wj = redi[w2][tid];
        if (wv > bv || (wv == bv && wj < bj)) { bv = wv; bj = wj; }
      }
      invrs_sh[tid] = 1.f/(ss + EPS);
      idxout[b*200 + i0 + tid] = bj;
    }
    __syncthreads();

    // phase 2: lane = k
    int kl = min(tid, 199); bool kv = tid < 200;
    float acw[8];
#pragma unroll
    for (int ii = 0; ii < 8; ii++) acw[ii] = 0.f;
    for (int j0 = 0; j0 < 200; j0 += 4) {
      float qv0 = qb[(j0+0)*200 + kl];
      float qv1 = qb[(j0+1)*200 + kl];
      float qv2 = qb[(j0+2)*200 + kl];
      float qv3 = qb[(j0+3)*200 + kl];
#pragma unroll
      for (int ii = 0; ii < 8; ii++) {
        float4 rs = *(const float4*)&relsh[ii][j0];
        acw[ii] = fmaf(rs.x, qv0, acw[ii]);
        acw[ii] = fmaf(rs.y, qv1, acw[ii]);
        acw[ii] = fmaf(rs.z, qv2, acw[ii]);
        acw[ii] = fmaf(rs.w, qv3, acw[ii]);
      }
    }
#pragma unroll
    for (int ii = 0; ii < 8; ii++) {
      float v = acw[ii]*invrs_sh[ii];
      if (kv) wq[(size_t)(b*200 + i0 + ii)*200 + tid] = v;
    }
  }
}

// k_max: maxpool only (v16). 320 blocks (32 b x 10 cgroups of 5 c), 512 thr.
// 16x16x32 engine; paired j-tiles with independent C0/C1 chains (2-way ILP).
__global__ __launch_bounds__(512) void k_max(
    const unsigned short* __restrict__ db16, const unsigned short* __restrict__ qb16,
    const float* __restrict__ m2all, const float* __restrict__ invmqn,
    float* __restrict__ pmax2, float* __restrict__ psum2)
{
  __shared__ __align__(16) unsigned short qsh[208*218 + 8];  // 90,704 B
  __shared__ __align__(16) float m2sh[5*224];                // k>=200 zeroed
  __shared__ float iqsh[5*208];                              // j>=200 zeroed
  int tid = threadIdx.x;
  int w = tid >> 6, lane = tid & 63;
  int b = blockIdx.x / 10, cg = blockIdx.x % 10;

  {
    const unsigned short* src = qb16 + (size_t)b*256*208;
    for (int s = tid; s < 208*26; s += 512) {
      int r = s / 26, ch = s - r*26;
      *(bf16x8*)(qsh + r*218 + ch*8) =
          *(const bf16x8*)(src + (size_t)r*208 + ch*8);
    }
    // zero row pads [208,218) (5 x uint per row) and the 8-elem tail
    for (int s = tid; s < 208*5; s += 512) {
      int r = s / 5, p = s - r*5;
      *(unsigned int*)(qsh + r*218 + 208 + p*2) = 0u;
    }
    if (tid < 4) *(unsigned int*)(qsh + 208*218 + tid*2) = 0u;
    for (int s = tid; s < 5*224; s += 512) {
      int cl = s / 224, k = s - cl*224;
      m2sh[s] = (k < 200) ? m2all[10000 + (cg*5 + cl)*200 + k] : 0.f;
    }
    for (int s = tid; s < 5*208; s += 512) {
      int cl = s / 208, jj = s - cl*208;
      iqsh[s] = (jj < 200) ? invmqn[(size_t)(cg*5 + cl)*6400 + b*200 + jj] : 0.f;
    }
  }
  __syncthreads();

  int r16 = lane & 15, g = lane >> 4;      // A-row / B-col index; k-octet
  bool hi_ok = g < 2;                       // chunk-6 k in [192,208) valid
  // 65 tasks: (i-16-tile in [0,13)) x (c-local in [0,5)).
  for (int t = w; t < 65; t += 8) {
    int it = t % 13, cl = t / 13;
    int c = cg*5 + cl;

    // A-fragments: bf16 d row, scaled in place by m2 (f32 LDS).
    const unsigned short* dbp =
        db16 + (size_t)(b*256 + it*16 + r16)*208 + g*8;
    const float* m2p = m2sh + cl*224 + g*8;
    bf16x8 afc[7];
#pragma unroll
    for (int ks = 0; ks < 6; ks++) afc[ks] = *(const bf16x8*)(dbp + ks*32);
    afc[6] = *(const bf16x8*)(dbp + (hi_ok ? 192 : 0));
#pragma unroll
    for (int ks = 0; ks < 7; ks++) {
      float4 m0 = *(const float4*)(m2p + ks*32);
      float4 m1 = *(const float4*)(m2p + ks*32 + 4);
      bf16x8 a = afc[ks];
      a[0] = (__bf16)((float)a[0]*m0.x); a[1] = (__bf16)((float)a[1]*m0.y);
      a[2] = (__bf16)((float)a[2]*m0.z); a[3] = (__bf16)((float)a[3]*m0.w);
      a[4] = (__bf16)((float)a[4]*m1.x); a[5] = (__bf16)((float)a[5]*m1.y);
      a[6] = (__bf16)((float)a[6]*m1.z); a[7] = (__bf16)((float)a[7]*m1.w);
      afc[ks] = a;
    }

    float vm[4], vs[4];
#pragma unroll
    for (int r = 0; r < 4; r++) { vm[r] = NEG_HUGE; vs[r] = 0.f; }
    const float* iqp = iqsh + cl*208;

    // 6 pairs of j-tiles (jt = 2p, 2p+1; j <= 191 so always valid) with
    // independent accumulator chains; pinned unroll 1 bounds the live set.
#pragma unroll 1
    for (int p = 0; p < 6; p++) {
      const unsigned short* b0 = qsh + (p*32 + r16)*218 + g*8;
      const unsigned short* b1 = b0 + 16*218;
      f32x4 C0, C1;
#pragma unroll
      for (int z = 0; z < 4; z++) { C0[z] = 0.f; C1[z] = 0.f; }
#pragma unroll
      for (int ks = 0; ks < 7; ks++) {
        bf16x8 f0 = *(const bf16x8*)(b0 + ks*32);
        bf16x8 f1 = *(const bf16x8*)(b1 + ks*32);
        C0 = __builtin_amdgcn_mfma_f32_16x16x32_bf16(afc[ks], f0, C0, 0, 0, 0);
        C1 = __builtin_amdgcn_mfma_f32_16x16x32_bf16(afc[ks], f1, C1, 0, 0, 0);
      }
      int j0 = p*32 + r16;
      float iq0 = iqp[j0], iq1 = iqp[j0 + 16];
#pragma unroll
      for (int r = 0; r < 4; r++) {
        float v0 = C0[r]*iq0, v1 = C1[r]*iq1;
        vs[r] += v0; vs[r] += v1;
        vm[r] = fmaxf(vm[r], v0);
        vm[r] = fmaxf(vm[r], v1);
      }
    }
    {   // tail j-tile jt=12: j in [192,208)
      f32x4 C;
#pragma unroll
      for (int z = 0; z < 4; z++) C[z] = 0.f;
      const unsigned short* bptr = qsh + (192 + r16)*218 + g*8;
#pragma unroll
      for (int ks = 0; ks < 7; ks++) {
        bf16x8 bf = *(const bf16x8*)(bptr + ks*32);
        C = __builtin_amdgcn_mfma_f32_16x16x32_bf16(afc[ks], bf, C, 0, 0, 0);
      }
      int j = 192 + r16;
      bool jvld = j < 200;
      float iqj = iqp[j];               // zero-padded for j>=200
#pragma unroll
      for (int r = 0; r < 4; r++) {
        float v = C[r]*iqj;
        vs[r] += v;
        vm[r] = fmaxf(vm[r], jvld ? v : NEG_HUGE);
      }
    }

    // reduce over j (across the 16-lane col groups; row-group g preserved)
#pragma unroll
    for (int r = 0; r < 4; r++) {
      float a2 = vm[r], s2 = vs[r];
#pragma unroll
      for (int m = 1; m <= 8; m <<= 1) {
        a2 = fmaxf(a2, __shfl_xor(a2, m));
        s2 += __shfl_xor(s2, m);
      }
      vm[r] = a2; vs[r] = s2;
    }
    if (r16 == 0) {
      size_t base = (size_t)(b*50 + c)*256;
#pragma unroll
      for (int r = 0; r < 4; r++) {
        int i = it*16 + g*4 + r;             // C row = g*4 + reg
        pmax2[base + i] = vm[r];
        psum2[base + i] = vs[r];
      }
    }
  }
}

// k_gemm2: exact r10-proven body, own kernel. 200 blocks x 512 thr,
// 8 wave-tasks per block, 1600 tasks.
__global__ __launch_bounds__(512,2) void k_gemm2(
    const float* __restrict__ dR, const float* __restrict__ qR,
    const float* __restrict__ qL, const float* __restrict__ wq,
    const int* __restrict__ idx, const unsigned short* __restrict__ m2b16,
    float* __restrict__ G)
{
  int tid = threadIdx.x;
  int w = tid >> 6, lane = tid & 63;
  int n = lane & 31, h = lane >> 5;
  int task = blockIdx.x*8 + w;             // [0,1600)
  int mp = task / 400;
  int sub = task % 400;
  int rt = sub >> 1, nt = sub & 1;
  int row = rt*32 + n;                     // < 6400
  int bb = row / 200;
  int msel = (mp == 0) ? 0 : (mp == 3) ? 3 : 2;

  const float* s0 = dR + (size_t)row*200;
  const float* s1;
  if (mp == 0)      s1 = qL + (size_t)bb*200;
  else if (mp == 1) s1 = wq + (size_t)row*200;
  else if (mp == 2) { s0 = wq + (size_t)row*200; s1 = s0; }
  else              s1 = qR + (size_t)(bb*200 + idx[row])*200;

  bf16x8 afrag[13];
#pragma unroll
  for (int ks = 0; ks < 13; ks++) {
    int ko = ks*16 + h*8;
    bf16x8 af;
    if (ko < 200) {
      float4 a0 = *(const float4*)(s0 + ko);
      float4 a1 = *(const float4*)(s0 + ko + 4);
      float4 b0 = *(const float4*)(s1 + ko);
      float4 b1 = *(const float4*)(s1 + ko + 4);
      af[0] = (__bf16)(a0.x*b0.x); af[1] = (__bf16)(a0.y*b0.y);
      af[2] = (__bf16)(a0.z*b0.z); af[3] = (__bf16)(a0.w*b0.w);
      af[4] = (__bf16)(a1.x*b1.x); af[5] = (__bf16)(a1.y*b1.y);
      af[6] = (__bf16)(a1.z*b1.z); af[7] = (__bf16)(a1.w*b1.w);
    } else {
#pragma unroll
      for (int z = 0; z < 8; z++) af[z] = (__bf16)0.0f;
    }
    afrag[ks] = af;
  }

  f32x16 C;
#pragma unroll
  for (int z = 0; z < 16; z++) C[z] = 0.f;
  const unsigned short* bp = m2b16 + (size_t)(msel*50 + nt*32 + n)*208 + h*8;
#pragma unroll
  for (int ks = 0; ks < 13; ks++) {
    bf16x8 bf = *(const bf16x8*)(bp + ks*16);
    C = __builtin_amdgcn_mfma_f32_32x32x16_bf16(afrag[ks], bf, C, 0, 0, 0);
  }
  int cc = nt*32 + n;
  if (cc < 50) {
#pragma unroll
    for (int r = 0; r < 16; r++) {
      int mrow = (r & 3) + 8*(r >> 2) + 4*h;
      G[(size_t)(mp*6400 + rt*32 + mrow)*50 + cc] = C[r];
    }
  }
}

// Final assembly: out[row][0:250] written lane-coalesced.
__global__ void k_out(
    const float* __restrict__ G, const float* __restrict__ pmax2,
    const float* __restrict__ psum2, const float* __restrict__ invfpn,
    const float* __restrict__ invmpn, const float* __restrict__ invapn,
    const float* __restrict__ invxpn, const float* __restrict__ invfqn,
    const float* __restrict__ invxqn, const int* __restrict__ idx,
    float* __restrict__ out)
{
  int row = blockIdx.x;
  int l = threadIdx.x;
  if (l >= 250) return;
  int b = row / 200, i = row % 200;
  int seg = l / 50, c = l % 50;
  float o;
  if (seg == 0) {
    o = G[(size_t)(0*6400 + row)*50 + c] * invfpn[row*50 + c] * invfqn[b*50 + c];
  } else if (seg == 1) {
    o = pmax2[(size_t)(b*50 + c)*256 + i] * invmpn[row*50 + c];
  } else if (seg == 2) {
    o = psum2[(size_t)(b*50 + c)*256 + i] * invmpn[row*50 + c] * (1.f/200.f);
  } else if (seg == 3) {
    o = G[(size_t)(1*6400 + row)*50 + c] * invapn[row*50 + c]
        * rsqrtf(fmaxf(G[(size_t)(2*6400 + row)*50 + c], EPS));
  } else {
    int jid = idx[row];
    o = G[(size_t)(3*6400 + row)*50 + c] * invxpn[row*50 + c]
        * invxqn[(b*200 + jid)*50 + c];
  }
  out[(size_t)row*250 + l] = o;
}

extern "C" void kernel_launch(void* const* d_in, const int* in_sizes, int n_in,
                              void* d_out, int out_size, void* d_ws, size_t ws_size,
                              hipStream_t stream) {
  const float* qR = (const float*)d_in[0];
  const float* qL = (const float*)d_in[1];
  const float* qM = (const float*)d_in[2];
  const float* dR = (const float*)d_in[3];
  // d_in[4] = d_last: unused by the reference
  const float* dM = (const float*)d_in[5];
  const float* fullM = (const float*)d_in[6];
  const float* mpM   = (const float*)d_in[7];
  const float* attM  = (const float*)d_in[8];
  const float* xM    = (const float*)d_in[9];

  float* ws  = (float*)d_ws;
  float* out = (float*)d_out;

  float* m2all  = ws + OFF_M2ALL;
  unsigned short* m2b16 = (unsigned short*)(ws + OFF_M2B16);
  unsigned short* qb16 = (unsigned short*)(ws + OFF_QB16);
  unsigned short* db16 = (unsigned short*)(ws + OFF_DB16);
  float* invfpn = ws + OFF_INVFPN;
  float* invmpn = ws + OFF_INVMPN;
  float* invapn = ws + OFF_INVAPN;
  float* invxpn = ws + OFF_INVXPN;
  float* invmqn = ws + OFF_INVMQN;
  float* invxqn = ws + OFF_INVXQN;
  float* invfqn = ws + OFF_INVFQN;
  float* invdn  = ws + OFF_INVDN;
  float* invqn  = ws + OFF_INVQN;
  int*   idxp   = (int*)(ws + OFF_IDX);
  float* wqp    = ws + OFF_WQ;
  float* G      = ws + OFF_G;
  float* pmax2  = ws + OFF_PMAX2;
  float* psum2  = ws + OFF_PSUM2;

  k_prep<<<4278, 256, 0, stream>>>(qR, dR, fullM, mpM, attM, xM,
                                   qb16, db16, invdn, invqn, m2all, m2b16);
  k_mid<<<1502, 256, 0, stream>>>(dR, qR, qL, m2b16,
                                  invfpn, invmpn, invapn, invxpn,
                                  invmqn, invxqn, invfqn,
                                  qM, dM, invdn, invqn, wqp, idxp);
  k_max<<<320, 512, 0, stream>>>(db16, qb16, m2all, invmqn, pmax2, psum2);
  k_gemm2<<<200, 512, 0, stream>>>(dR, qR, qL, wqp, idxp, m2b16, G);
  k_out<<<6400, 256, 0, stream>>>(G, pmax2, psum2, invfpn, invmpn, invapn,
                                  invxpn, invfqn, invxqn, idxp, out);
}

// Round 7
// 246.933 us; speedup vs baseline: 2.0688x; 1.9772x over previous
//
#include <hip/hip_runtime.h>
#include <math.h>

// MultiPerspectiveMatch on MI355X — round 17 = exact revert to r10 (246.8us,
// the session best). Rounds 11-16 (c-amortized maxpool: shared q tile, d-side
// scaling, 1 block/CU, 8-wave) all landed 3-5x WORSE (335-625us) from a mix of
// a hard 128-VGPR grant (spill -> 600MB scratch) and an unexplained ~2-4K
// cycle/iter latency wall at 2 waves/SIMD that survived ILP pairing (r16 null:
// VGPR unchanged 88 -> compiler re-serialized). Lesson recorded: r10's
// per-(b,c) staging-fused maxpool at 2 blocks/CU / 4 waves/SIMD is the proven
// structure; re-anchor here. Next lever: the ~143us k_prep/k_mid/k_out
// residue, untouched all session.

#define EPS 1e-6f
#define NEG_HUGE -3.4e38f

typedef __bf16 bf16x8 __attribute__((ext_vector_type(8)));
typedef float f32x16 __attribute__((ext_vector_type(16)));

// ---- ws offsets (floats) ----
constexpr size_t OFF_M2ALL = 0;            // f32 [4][50][200] = 40,000
constexpr size_t OFF_M2B16 = 40000;        // bf16 [224][208] = 23,296 fl
constexpr size_t OFF_QB16  = 63296;        // bf16 [32][256][208] = 851,968 fl
constexpr size_t OFF_DB16  = 915264;       // bf16 [32][256][208] = 851,968 fl
constexpr size_t OFF_INVFPN= 1767232;      // [6400][50]
constexpr size_t OFF_INVMPN= 2087232;
constexpr size_t OFF_INVAPN= 2407232;
constexpr size_t OFF_INVXPN= 2727232;
constexpr size_t OFF_INVMQN= 3047232;      // [c(50)][6400]
constexpr size_t OFF_INVXQN= 3367232;      // [6400][50]
constexpr size_t OFF_INVFQN= 3687232;      // [32][50]
constexpr size_t OFF_INVDN = 3688832;      // [6400]
constexpr size_t OFF_INVQN = 3695232;      // [6400]
constexpr size_t OFF_IDX   = 3701632;      // int [6400]
constexpr size_t OFF_WQ    = 3708032;      // [32][200][200] = 1,280,000
constexpr size_t OFF_G     = 4988032;      // [4][6400][50] = 1,280,000
constexpr size_t OFF_PMAX2 = 6268032;      // [1600][256]
constexpr size_t OFF_PSUM2 = 6677632;      // [1600][256]
// end = 7,087,232 floats = 28.3 MB

// Fused prep: blocks [0,4096): d/q rows -> bf16 padded [32][256][208] + plain
// norms (one row per wave). Blocks [4096, 4278): M^2 tables (f32 + bf16).
__global__ __launch_bounds__(256) void k_prep(
    const float* __restrict__ qR, const float* __restrict__ dR,
    const float* __restrict__ fM, const float* __restrict__ mM,
    const float* __restrict__ aM, const float* __restrict__ xM,
    unsigned short* __restrict__ qb16, unsigned short* __restrict__ db16,
    float* __restrict__ invdn, float* __restrict__ invqn,
    float* __restrict__ m2all, unsigned short* __restrict__ m2b16)
{
  int blk = blockIdx.x;
  int tid = threadIdx.x;
  if (blk < 4096) {
    int task = blk*4 + (tid >> 6);        // 0..16383
    int l = tid & 63;
    int isQ = task >= 8192;
    int r = isQ ? task - 8192 : task;     // b*256 + j
    int b = r >> 8, j = r & 255;
    unsigned short* dst = (isQ ? qb16 : db16) + (size_t)r*208;
    if (j < 200) {
      const float* src = (isQ ? qR : dR) + (size_t)(b*200 + j)*200;
      float4 v = {0.f,0.f,0.f,0.f};
      if (l < 50) v = *(const float4*)(src + l*4);
      float s = fmaf(v.x,v.x, fmaf(v.y,v.y, fmaf(v.z,v.z, v.w*v.w)));
#pragma unroll
      for (int m = 32; m; m >>= 1) s += __shfl_xor(s, m);
      if (l == 0) {
        float rr = rsqrtf(fmaxf(s, EPS));
        if (isQ) invqn[b*200 + j] = rr; else invdn[b*200 + j] = rr;
      }
      if (l < 52) {
        ushort4 o = {0,0,0,0};
        if (l < 50) {
          __bf16 h0=(__bf16)v.x, h1=(__bf16)v.y, h2=(__bf16)v.z, h3=(__bf16)v.w;
          o.x = *(unsigned short*)&h0; o.y = *(unsigned short*)&h1;
          o.z = *(unsigned short*)&h2; o.w = *(unsigned short*)&h3;
        }
        *(ushort4*)(dst + l*4) = o;
      }
    } else {
      if (l < 52) { ushort4 z = {0,0,0,0}; *(ushort4*)(dst + l*4) = z; }
    }
  } else {
    int i = (blk - 4096)*256 + tid;
    if (i < 40000) {
      int m = i / 10000, r = i % 10000;
      const float* s = (m==0)?fM:(m==1)?mM:(m==2)?aM:xM;
      float v = s[r];
      m2all[i] = v*v;
    }
    if (i < 224*208) {
      int row = i / 208, k = i % 208;
      unsigned short o = 0;
      if (row < 200 && k < 200) {
        int m = row / 50, c = row % 50;
        const float* s = (m==0)?fM:(m==1)?mM:(m==2)?aM:xM;
        float v = s[c*200 + k];
        __bf16 h = (__bf16)(v*v);
        o = *(unsigned short*)&h;
      }
      m2b16[i] = o;
    }
  }
}

// k_mid: blocks [0,702) = gemm1 (nsq MFMA + fused rsqrt/scatter, one wave per
// (row-tile,nt), 2807 tasks); blocks [702,1502) = relwq (rel+wq fused, v3:
// per-lane direct global q rows, no qsh staging; relsh stays in LDS).
__global__ __launch_bounds__(256) void k_mid(
    const float* __restrict__ dR, const float* __restrict__ qR,
    const float* __restrict__ qL, const unsigned short* __restrict__ m2b16,
    float* __restrict__ invfpn, float* __restrict__ invmpn,
    float* __restrict__ invapn, float* __restrict__ invxpn,
    float* __restrict__ invmqn, float* __restrict__ invxqn,
    float* __restrict__ invfqn,
    const float* __restrict__ qMask, const float* __restrict__ dMask,
    const float* __restrict__ invdn, const float* __restrict__ invqn,
    float* __restrict__ wq, int* __restrict__ idxout)
{
  int tid = threadIdx.x;
  if (blockIdx.x < 702) {
    // ---------------- gemm1 role ----------------
    int w = tid >> 6, lane = tid & 63;
    int n = lane & 31, h = lane >> 5;
    int task = blockIdx.x*4 + w;
    if (task >= 2807) return;             // wave-uniform
    int rt = task / 7, nt = task % 7;     // rt in [0,401), 401*32 = 12832
    int row = rt*32 + n;

    const float* src;
    if (row < 6400)       src = dR + (size_t)row*200;
    else if (row < 12800) src = qR + (size_t)(row-6400)*200;
    else                  src = qL + (size_t)(row-12800)*200;

    bf16x8 afrag[13];
#pragma unroll
    for (int ks = 0; ks < 13; ks++) {
      int ko = ks*16 + h*8;
      bf16x8 af;
      if (ko < 200) {
        float4 a0 = *(const float4*)(src + ko);
        float4 a1 = *(const float4*)(src + ko + 4);
        af[0] = (__bf16)(a0.x*a0.x); af[1] = (__bf16)(a0.y*a0.y);
        af[2] = (__bf16)(a0.z*a0.z); af[3] = (__bf16)(a0.w*a0.w);
        af[4] = (__bf16)(a1.x*a1.x); af[5] = (__bf16)(a1.y*a1.y);
        af[6] = (__bf16)(a1.z*a1.z); af[7] = (__bf16)(a1.w*a1.w);
      } else {
#pragma unroll
        for (int z = 0; z < 8; z++) af[z] = (__bf16)0.0f;
      }
      afrag[ks] = af;
    }

    f32x16 C;
#pragma unroll
    for (int z = 0; z < 16; z++) C[z] = 0.f;
    const unsigned short* bp = m2b16 + (size_t)(nt*32 + n)*208 + h*8;
#pragma unroll
    for (int ks = 0; ks < 13; ks++) {
      bf16x8 bf = *(const bf16x8*)(bp + ks*16);
      C = __builtin_amdgcn_mfma_f32_32x32x16_bf16(afrag[ks], bf, C, 0, 0, 0);
    }

    int cp = nt*32 + n;                   // c' = m*50 + c
    if (cp < 200) {
      int m = cp / 50, c = cp % 50;
#pragma unroll
      for (int r = 0; r < 16; r++) {
        int grow = rt*32 + (r & 3) + 8*(r >> 2) + 4*h;
        float v = rsqrtf(fmaxf(C[r], EPS));
        if (grow < 6400) {
          if (m == 0)      invfpn[grow*50 + c] = v;
          else if (m == 1) invmpn[grow*50 + c] = v;
          else if (m == 2) invapn[grow*50 + c] = v;
          else             invxpn[grow*50 + c] = v;
        } else if (grow < 12800) {
          int r2 = grow - 6400;
          if (m == 1)      invmqn[c*6400 + r2] = v;
          else if (m == 3) invxqn[r2*50 + c] = v;
        } else {
          if (m == 0)      invfqn[(grow-12800)*50 + c] = v;
        }
      }
    }
  } else {
    // ---------------- relwq role ----------------
    __shared__ float relsh[8][256];            // 8 KB
    __shared__ float redv[4][8][2];
    __shared__ int   redi[4][8];
    __shared__ float invrs_sh[8];
    int blk = blockIdx.x - 702;
    int b  = blk / 25;
    int i0 = (blk % 25) * 8;
    int j = tid, jr = min(j, 199);
    bool jv = j < 200;
    const float* qb = qR + b*40000;
    const float* db = dR + (b*200 + i0)*200;
    float acc[8];
#pragma unroll
    for (int ii = 0; ii < 8; ii++) acc[ii] = 0.f;

    // phase 1: lane=j, q row read direct from global (L2-resident).
    const float* qrow = qb + jr*200;
    for (int k4 = 0; k4 < 200; k4 += 4) {
      float4 qv = *(const float4*)(qrow + k4);
#pragma unroll
      for (int ii = 0; ii < 8; ii++) {
        acc[ii] = fmaf(db[ii*200 + k4 + 0], qv.x, acc[ii]);
        acc[ii] = fmaf(db[ii*200 + k4 + 1], qv.y, acc[ii]);
        acc[ii] = fmaf(db[ii*200 + k4 + 2], qv.z, acc[ii]);
        acc[ii] = fmaf(db[ii*200 + k4 + 3], qv.w, acc[ii]);
      }
    }

    float iqn = invqn[b*200 + jr];
    float qm  = qMask[b*200 + jr];
    int w = tid >> 6, l = tid & 63;
    float rv[8];
#pragma unroll
    for (int ii = 0; ii < 8; ii++) {
      float idn = invdn[b*200 + i0 + ii];
      float dm  = dMask[b*200 + i0 + ii];
      float r = acc[ii]*iqn*idn*qm*dm;
      rv[ii] = r;
      relsh[ii][j] = jv ? r : 0.f;
    }
#pragma unroll
    for (int ii = 0; ii < 8; ii++) {
      float vm = jv ? rv[ii] : NEG_HUGE;
      float vs = jv ? rv[ii] : 0.f;
      int bj = jr;
#pragma unroll
      for (int m = 32; m; m >>= 1) {
        float ov = __shfl_xor(vm, m);
        int   oj = __shfl_xor(bj, m);
        vs += __shfl_xor(vs, m);
        if (ov > vm || (ov == vm && oj < bj)) { vm = ov; bj = oj; }  // first-max
      }
      if (l == 0) { redv[w][ii][0] = vm; redv[w][ii][1] = vs; redi[w][ii] = bj; }
    }
    __syncthreads();
    if (tid < 8) {
      float bv = redv[0][tid][0], ss = redv[0][tid][1]; int bj = redi[0][tid];
      for (int w2 = 1; w2 < 4; w2++) {
        ss += redv[w2][tid][1];
        float wv = redv[w2][tid][0]; int wj = redi[w2][tid];
        if (wv > bv || (wv == bv && wj < bj)) { bv = wv; bj = wj; }
      }
      invrs_sh[tid] = 1.f/(ss + EPS);
      idxout[b*200 + i0 + tid] = bj;
    }
    __syncthreads();

    // phase 2: lane = k
    int kl = min(tid, 199); bool kv = tid < 200;
    float acw[8];
#pragma unroll
    for (int ii = 0; ii < 8; ii++) acw[ii] = 0.f;
    for (int j0 = 0; j0 < 200; j0 += 4) {
      float qv0 = qb[(j0+0)*200 + kl];
      float qv1 = qb[(j0+1)*200 + kl];
      float qv2 = qb[(j0+2)*200 + kl];
      float qv3 = qb[(j0+3)*200 + kl];
#pragma unroll
      for (int ii = 0; ii < 8; ii++) {
        float4 rs = *(const float4*)&relsh[ii][j0];
        acw[ii] = fmaf(rs.x, qv0, acw[ii]);
        acw[ii] = fmaf(rs.y, qv1, acw[ii]);
        acw[ii] = fmaf(rs.z, qv2, acw[ii]);
        acw[ii] = fmaf(rs.w, qv3, acw[ii]);
      }
    }
#pragma unroll
    for (int ii = 0; ii < 8; ii++) {
      float v = acw[ii]*invrs_sh[ii];
      if (kv) wq[(size_t)(b*200 + i0 + ii)*200 + tid] = v;
    }
  }
}

// k_big: blocks [0,1600) = maxpool (long pole, dispatched first);
// blocks [1600,1800) = gemm2 (8 wave-tasks per 512-thr block, 1600 tasks).
__global__ __launch_bounds__(512,2) void k_big(
    const unsigned short* __restrict__ db16, const unsigned short* __restrict__ qb16,
    const float* __restrict__ m2all, const float* __restrict__ invmqn,
    float* __restrict__ pmax2, float* __restrict__ psum2,
    const float* __restrict__ dR, const float* __restrict__ qR,
    const float* __restrict__ qL, const float* __restrict__ wq,
    const int* __restrict__ idx, const unsigned short* __restrict__ m2b16,
    float* __restrict__ G)
{
  int tid = threadIdx.x;
  int w = tid >> 6, lane = tid & 63;
  int n = lane & 31, h = lane >> 5;
  if (blockIdx.x < 1600) {
    // ---------------- maxpool role (identical to r9 v6) ----------------
    __shared__ __align__(16) unsigned short qsh[128*216];  // 55296 B
    int b = blockIdx.x / 50, c = blockIdx.x % 50;
    const float* M2 = m2all + 10000 + c*200;
    const unsigned short* dbp = db16 + (size_t)(b*256 + w*32 + n)*208 + h*8;

    bf16x8 afrag[13];
#pragma unroll
    for (int ks = 0; ks < 13; ks++) afrag[ks] = *(const bf16x8*)(dbp + ks*16);

    float vm[16], vs[16];
#pragma unroll
    for (int r = 0; r < 16; r++) { vm[r] = NEG_HUGE; vs[r] = 0.f; }

    for (int jh = 0; jh < 2; jh++) {
      int nrows = jh ? 96 : 128;
      int njt   = jh ? 3 : 4;
      __syncthreads();
      {
        const unsigned short* src = qb16 + (size_t)(b*256 + jh*128)*208;
        const float* iqb = invmqn + c*6400 + b*200;
        for (int s = tid; s < nrows*26; s += 512) {
          int r = s / 26, ch = s - r*26;
          int j = jh*128 + r;
          float iq = (j < 200) ? iqb[j] : 0.f;
          int k0 = ch*8;
          bf16x8 v = *(const bf16x8*)(src + (size_t)r*208 + k0);
          float4 m0 = *(const float4*)(M2 + k0);     // k0=200 reads past-row
          float4 m1 = *(const float4*)(M2 + k0 + 4); // data: finite, x0=0. ok
          bf16x8 o;
          o[0] = (__bf16)((float)v[0]*iq*m0.x); o[1] = (__bf16)((float)v[1]*iq*m0.y);
          o[2] = (__bf16)((float)v[2]*iq*m0.z); o[3] = (__bf16)((float)v[3]*iq*m0.w);
          o[4] = (__bf16)((float)v[4]*iq*m1.x); o[5] = (__bf16)((float)v[5]*iq*m1.y);
          o[6] = (__bf16)((float)v[6]*iq*m1.z); o[7] = (__bf16)((float)v[7]*iq*m1.w);
          *(bf16x8*)(qsh + r*216 + k0) = o;
        }
      }
      __syncthreads();

      for (int jt = 0; jt < njt; jt++) {
        f32x16 C;
#pragma unroll
        for (int z = 0; z < 16; z++) C[z] = 0.f;
        const unsigned short* bptr = qsh + (jt*32 + n)*216 + h*8;
#pragma unroll
        for (int ks = 0; ks < 13; ks++) {
          bf16x8 bf = *(const bf16x8*)(bptr + ks*16);
          C = __builtin_amdgcn_mfma_f32_32x32x16_bf16(afrag[ks], bf, C, 0, 0, 0);
        }
        bool jv = (jh*128 + jt*32 + n) < 200;
#pragma unroll
        for (int r = 0; r < 16; r++) {
          vm[r] = fmaxf(vm[r], jv ? C[r] : NEG_HUGE);
          vs[r] += C[r];
        }
      }
    }

#pragma unroll
    for (int r = 0; r < 16; r++) {
      float a = vm[r], s = vs[r];
#pragma unroll
      for (int m = 1; m <= 16; m <<= 1) {
        a = fmaxf(a, __shfl_xor(a, m));
        s += __shfl_xor(s, m);
      }
      vm[r] = a; vs[r] = s;
    }
    if (n == 0) {
#pragma unroll
      for (int r = 0; r < 16; r++) {
        int i = w*32 + (r & 3) + 8*(r >> 2) + 4*h;
        pmax2[(size_t)blockIdx.x*256 + i] = vm[r];
        psum2[(size_t)blockIdx.x*256 + i] = vs[r];
      }
    }
  } else {
    // ---------------- gemm2 role ----------------
    int task = (blockIdx.x - 1600)*8 + w;    // [0,1600)
    int mp = task / 400;
    int sub = task % 400;
    int rt = sub >> 1, nt = sub & 1;
    int row = rt*32 + n;                     // < 6400
    int bb = row / 200;
    int msel = (mp == 0) ? 0 : (mp == 3) ? 3 : 2;

    const float* s0 = dR + (size_t)row*200;
    const float* s1;
    if (mp == 0)      s1 = qL + (size_t)bb*200;
    else if (mp == 1) s1 = wq + (size_t)row*200;
    else if (mp == 2) { s0 = wq + (size_t)row*200; s1 = s0; }
    else              s1 = qR + (size_t)(bb*200 + idx[row])*200;

    bf16x8 afrag[13];
#pragma unroll
    for (int ks = 0; ks < 13; ks++) {
      int ko = ks*16 + h*8;
      bf16x8 af;
      if (ko < 200) {
        float4 a0 = *(const float4*)(s0 + ko);
        float4 a1 = *(const float4*)(s0 + ko + 4);
        float4 b0 = *(const float4*)(s1 + ko);
        float4 b1 = *(const float4*)(s1 + ko + 4);
        af[0] = (__bf16)(a0.x*b0.x); af[1] = (__bf16)(a0.y*b0.y);
        af[2] = (__bf16)(a0.z*b0.z); af[3] = (__bf16)(a0.w*b0.w);
        af[4] = (__bf16)(a1.x*b1.x); af[5] = (__bf16)(a1.y*b1.y);
        af[6] = (__bf16)(a1.z*b1.z); af[7] = (__bf16)(a1.w*b1.w);
      } else {
#pragma unroll
        for (int z = 0; z < 8; z++) af[z] = (__bf16)0.0f;
      }
      afrag[ks] = af;
    }

    f32x16 C;
#pragma unroll
    for (int z = 0; z < 16; z++) C[z] = 0.f;
    const unsigned short* bp = m2b16 + (size_t)(msel*50 + nt*32 + n)*208 + h*8;
#pragma unroll
    for (int ks = 0; ks < 13; ks++) {
      bf16x8 bf = *(const bf16x8*)(bp + ks*16);
      C = __builtin_amdgcn_mfma_f32_32x32x16_bf16(afrag[ks], bf, C, 0, 0, 0);
    }
    int cc = nt*32 + n;
    if (cc < 50) {
#pragma unroll
      for (int r = 0; r < 16; r++) {
        int mrow = (r & 3) + 8*(r >> 2) + 4*h;
        G[(size_t)(mp*6400 + rt*32 + mrow)*50 + cc] = C[r];
      }
    }
  }
}

// Final assembly: out[row][0:250] written lane-coalesced.
__global__ void k_out(
    const float* __restrict__ G, const float* __restrict__ pmax2,
    const float* __restrict__ psum2, const float* __restrict__ invfpn,
    const float* __restrict__ invmpn, const float* __restrict__ invapn,
    const float* __restrict__ invxpn, const float* __restrict__ invfqn,
    const float* __restrict__ invxqn, const int* __restrict__ idx,
    float* __restrict__ out)
{
  int row = blockIdx.x;
  int l = threadIdx.x;
  if (l >= 250) return;
  int b = row / 200, i = row % 200;
  int seg = l / 50, c = l % 50;
  float o;
  if (seg == 0) {
    o = G[(size_t)(0*6400 + row)*50 + c] * invfpn[row*50 + c] * invfqn[b*50 + c];
  } else if (seg == 1) {
    o = pmax2[(size_t)(b*50 + c)*256 + i] * invmpn[row*50 + c];
  } else if (seg == 2) {
    o = psum2[(size_t)(b*50 + c)*256 + i] * invmpn[row*50 + c] * (1.f/200.f);
  } else if (seg == 3) {
    o = G[(size_t)(1*6400 + row)*50 + c] * invapn[row*50 + c]
        * rsqrtf(fmaxf(G[(size_t)(2*6400 + row)*50 + c], EPS));
  } else {
    int jid = idx[row];
    o = G[(size_t)(3*6400 + row)*50 + c] * invxpn[row*50 + c]
        * invxqn[(b*200 + jid)*50 + c];
  }
  out[(size_t)row*250 + l] = o;
}

extern "C" void kernel_launch(void* const* d_in, const int* in_sizes, int n_in,
                              void* d_out, int out_size, void* d_ws, size_t ws_size,
                              hipStream_t stream) {
  const float* qR = (const float*)d_in[0];
  const float* qL = (const float*)d_in[1];
  const float* qM = (const float*)d_in[2];
  const float* dR = (const float*)d_in[3];
  // d_in[4] = d_last: unused by the reference
  const float* dM = (const float*)d_in[5];
  const float* fullM = (const float*)d_in[6];
  const float* mpM   = (const float*)d_in[7];
  const float* attM  = (const float*)d_in[8];
  const float* xM    = (const float*)d_in[9];

  float* ws  = (float*)d_ws;
  float* out = (float*)d_out;

  float* m2all  = ws + OFF_M2ALL;
  unsigned short* m2b16 = (unsigned short*)(ws + OFF_M2B16);
  unsigned short* qb16 = (unsigned short*)(ws + OFF_QB16);
  unsigned short* db16 = (unsigned short*)(ws + OFF_DB16);
  float* invfpn = ws + OFF_INVFPN;
  float* invmpn = ws + OFF_INVMPN;
  float* invapn = ws + OFF_INVAPN;
  float* invxpn = ws + OFF_INVXPN;
  float* invmqn = ws + OFF_INVMQN;
  float* invxqn = ws + OFF_INVXQN;
  float* invfqn = ws + OFF_INVFQN;
  float* invdn  = ws + OFF_INVDN;
  float* invqn  = ws + OFF_INVQN;
  int*   idxp   = (int*)(ws + OFF_IDX);
  float* wqp    = ws + OFF_WQ;
  float* G      = ws + OFF_G;
  float* pmax2  = ws + OFF_PMAX2;
  float* psum2  = ws + OFF_PSUM2;

  k_prep<<<4278, 256, 0, stream>>>(qR, dR, fullM, mpM, attM, xM,
                                   qb16, db16, invdn, invqn, m2all, m2b16);
  k_mid<<<1502, 256, 0, stream>>>(dR, qR, qL, m2b16,
                                  invfpn, invmpn, invapn, invxpn,
                                  invmqn, invxqn, invfqn,
                                  qM, dM, invdn, invqn, wqp, idxp);
  k_big<<<1800, 512, 0, stream>>>(db16, qb16, m2all, invmqn, pmax2, psum2,
                                  dR, qR, qL, wqp, idxp, m2b16, G);
  k_out<<<6400, 256, 0, stream>>>(G, pmax2, psum2, invfpn, invmpn, invapn,
                                  invxpn, invfqn, invxqn, idxp, out);
}